// Round 5
// baseline (33.082 us; speedup 1.0000x reference)
//
#include <hip/hip_runtime.h>
#include <hip/hip_bf16.h>
#include <float.h>

// Problem constants: B=16, M=4096.
#define NB 16
#define MPTS 4096
#define NPRED (NB * MPTS)          // 65536 pred points
#define GTQ 16                     // gt partitions (occupancy lever)
#define GTN (MPTS / GTQ)           // 256 gt points per block
#define P 4                        // pred points per thread
#define BLK 256
#define PREDS_PER_BLK (BLK * P)    // 1024
#define PCH (MPTS / PREDS_PER_BLK) // 4 pred chunks per batch
#define GUNROLL 8
#define FIN_BLOCKS 64

// Kernel 1: one block = (batch b, 1024-pred chunk, gt 16th).
// LDS: (-2gx,-2gy,-2gz,||g||^2) float4 per gt point (4 KB).
// Each thread owns P=4 pred points; 8 gt points per iter. Writes partial
// min d2 to pmin[gtq][pred] (dense, no atomics, no init needed).
// Also zeroes the finish-kernel's counter (visible at kernel end).
__global__ __launch_bounds__(BLK) void adds_main(
    const float* __restrict__ pred_R, const float* __restrict__ pred_t,
    const float* __restrict__ gt_R,   const float* __restrict__ gt_t,
    const float* __restrict__ mp,     float* __restrict__ pmin,
    unsigned* __restrict__ counter)
{
    __shared__ float4 g4[GTN];          // 4 KB

    const int b   = blockIdx.x & 15;
    const int pch = (blockIdx.x >> 4) & (PCH - 1);
    const int gtq = blockIdx.x >> 6;
    const int tid = threadIdx.x;

    if (blockIdx.x == 0 && tid == 0) *counter = 0u;   // reset for adds_finish

    // ---- stage gt partition into LDS (transform fused) ----
    float gR[9];
#pragma unroll
    for (int i = 0; i < 9; ++i) gR[i] = gt_R[b * 9 + i];
    const float gtx = gt_t[b * 3 + 0];
    const float gty = gt_t[b * 3 + 1];
    const float gtz = gt_t[b * 3 + 2];

    {
        const int nl = tid;                 // GTN == BLK
        const int n  = gtq * GTN + nl;
        const float mx = mp[n * 3 + 0];
        const float my = mp[n * 3 + 1];
        const float mz = mp[n * 3 + 2];
        const float gx = fmaf(gR[0], mx, fmaf(gR[1], my, fmaf(gR[2], mz, gtx)));
        const float gy = fmaf(gR[3], mx, fmaf(gR[4], my, fmaf(gR[5], mz, gty)));
        const float gz = fmaf(gR[6], mx, fmaf(gR[7], my, fmaf(gR[8], mz, gtz)));
        const float gn = fmaf(gx, gx, fmaf(gy, gy, gz * gz));
        g4[nl] = make_float4(-2.0f * gx, -2.0f * gy, -2.0f * gz, gn);
    }

    // ---- this thread's P pred points ----
    float pR[9];
#pragma unroll
    for (int i = 0; i < 9; ++i) pR[i] = pred_R[b * 9 + i];
    const float ptx = pred_t[b * 3 + 0];
    const float pty = pred_t[b * 3 + 1];
    const float ptz = pred_t[b * 3 + 2];

    float px[P], py[P], pz[P], pn[P];
#pragma unroll
    for (int p = 0; p < P; ++p) {
        const int m = pch * PREDS_PER_BLK + p * BLK + tid;  // coalesced per p
        const float mx = mp[m * 3 + 0];
        const float my = mp[m * 3 + 1];
        const float mz = mp[m * 3 + 2];
        px[p] = fmaf(pR[0], mx, fmaf(pR[1], my, fmaf(pR[2], mz, ptx)));
        py[p] = fmaf(pR[3], mx, fmaf(pR[4], my, fmaf(pR[5], mz, pty)));
        pz[p] = fmaf(pR[6], mx, fmaf(pR[7], my, fmaf(pR[8], mz, ptz)));
        pn[p] = fmaf(px[p], px[p], fmaf(py[p], py[p], pz[p] * pz[p]));
    }

    __syncthreads();

    // ---- min over partition: 8 gt points/iter, 32 pairs/iter ----
    float best0[P], best1[P];
#pragma unroll
    for (int p = 0; p < P; ++p) { best0[p] = FLT_MAX; best1[p] = FLT_MAX; }

    for (int n = 0; n < GTN; n += GUNROLL) {
        float4 h[GUNROLL];
#pragma unroll
        for (int u = 0; u < GUNROLL; ++u) h[u] = g4[n + u];
#pragma unroll
        for (int p = 0; p < P; ++p) {
            float s[GUNROLL];
#pragma unroll
            for (int u = 0; u < GUNROLL; ++u)
                s[u] = fmaf(h[u].x, px[p], fmaf(h[u].y, py[p], fmaf(h[u].z, pz[p], h[u].w)));
            best0[p] = fminf(best0[p], fminf(s[0], s[1]));   // v_min3_f32
            best1[p] = fminf(best1[p], fminf(s[2], s[3]));
            best0[p] = fminf(best0[p], fminf(s[4], s[5]));
            best1[p] = fminf(best1[p], fminf(s[6], s[7]));
        }
    }

#pragma unroll
    for (int p = 0; p < P; ++p) {
        const float smin = fminf(best0[p], best1[p]);
        const float d2 = fmaxf(pn[p] + smin, 0.0f);
        const int m = pch * PREDS_PER_BLK + p * BLK + tid;
        pmin[gtq * NPRED + b * MPTS + m] = d2;   // coalesced
    }
}

// Kernel 2: per pred point, min over 16 partials -> sqrt -> block sums;
// last block (counter pattern) reduces the 64 partials in fixed lane order
// (bit-deterministic) and writes the mean.
__global__ __launch_bounds__(1024) void adds_finish(
    const float* __restrict__ pmin, float* __restrict__ partial,
    unsigned* __restrict__ counter, float* __restrict__ out)
{
    __shared__ float wsum[16];
    __shared__ int is_last;
    const int tid = threadIdx.x;
    const int g = blockIdx.x * 1024 + tid;

    float m0 = FLT_MAX, m1 = FLT_MAX;
#pragma unroll
    for (int q = 0; q < GTQ; q += 2) {
        m0 = fminf(m0, pmin[(q + 0) * NPRED + g]);
        m1 = fminf(m1, pmin[(q + 1) * NPRED + g]);
    }
    float s = sqrtf(fminf(m0, m1));
#pragma unroll
    for (int off = 32; off > 0; off >>= 1) s += __shfl_down(s, off, 64);
    if ((tid & 63) == 0) wsum[tid >> 6] = s;
    __syncthreads();
    if (tid == 0) {
        float t = 0.0f;
#pragma unroll
        for (int w = 0; w < 16; ++w) t += wsum[w];
        partial[blockIdx.x] = t;
        __threadfence();                                   // release partial
        const unsigned old = __hip_atomic_fetch_add(
            counter, 1u, __ATOMIC_ACQ_REL, __HIP_MEMORY_SCOPE_AGENT);
        is_last = (old == FIN_BLOCKS - 1) ? 1 : 0;
    }
    __syncthreads();

    if (is_last && tid < 64) {
        float v = __hip_atomic_load(&partial[tid], __ATOMIC_RELAXED,
                                    __HIP_MEMORY_SCOPE_AGENT);
#pragma unroll
        for (int off = 32; off > 0; off >>= 1) v += __shfl_down(v, off, 64);
        if (tid == 0) out[0] = v * (1.0f / (float)NPRED);
    }
}

extern "C" void kernel_launch(void* const* d_in, const int* in_sizes, int n_in,
                              void* d_out, int out_size, void* d_ws, size_t ws_size,
                              hipStream_t stream) {
    const float* pred_R = (const float*)d_in[0];
    const float* pred_t = (const float*)d_in[1];
    const float* gt_R   = (const float*)d_in[2];
    const float* gt_t   = (const float*)d_in[3];
    const float* mp     = (const float*)d_in[4];
    float* out = (float*)d_out;

    char* ws = (char*)d_ws;
    float* pmin      = (float*)ws;                                   // 4 MB
    float* partial   = (float*)(ws + (size_t)GTQ * NPRED * 4);       // 64 floats
    unsigned* counter = (unsigned*)(ws + (size_t)GTQ * NPRED * 4 + 1024);

    adds_main<<<dim3(NB * PCH * GTQ), dim3(BLK), 0, stream>>>(
        pred_R, pred_t, gt_R, gt_t, mp, pmin, counter);
    adds_finish<<<dim3(FIN_BLOCKS), dim3(1024), 0, stream>>>(
        pmin, partial, counter, out);
}

// Round 6
// 32.545 us; speedup vs baseline: 1.0165x; 1.0165x over previous
//
#include <hip/hip_runtime.h>
#include <hip/hip_bf16.h>
#include <float.h>

// Problem constants: B=16, M=4096.
#define NB 16
#define MPTS 4096
#define NPRED (NB * MPTS)          // 65536 pred points
#define GTQ 32                     // gt partitions
#define GTN (MPTS / GTQ)           // 128 gt points per block
#define P 8                        // pred points per thread (LDS-pressure lever)
#define BLK 256
#define PREDS_PER_BLK (BLK * P)    // 2048
#define PCH (MPTS / PREDS_PER_BLK) // 2 pred chunks per batch
#define GUNROLL 4

// Kernel 1: one block = (batch b, 2048-pred chunk, gt 1/32).
// LDS: (-2gx,-2gy,-2gz,||g||^2) float4 per gt point (2 KB).
// Each thread owns P=8 pred points -> each ds_read_b128 feeds 8 fma-chains
// (LDS pipe at ~86% of VALU). Writes partial min d2 to pmin[gtq][pred]
// (dense, deterministic, no atomics, no init pass).
__global__ __launch_bounds__(BLK, 4) void adds_main(
    const float* __restrict__ pred_R, const float* __restrict__ pred_t,
    const float* __restrict__ gt_R,   const float* __restrict__ gt_t,
    const float* __restrict__ mp,     float* __restrict__ pmin)
{
    __shared__ float4 g4[GTN];          // 2 KB

    const int b   = blockIdx.x & 15;
    const int pch = (blockIdx.x >> 4) & (PCH - 1);
    const int gtq = blockIdx.x >> 5;
    const int tid = threadIdx.x;

    // ---- stage gt partition into LDS (transform fused); GTN=128 -> half waves ----
    if (tid < GTN) {
        float gR[9];
#pragma unroll
        for (int i = 0; i < 9; ++i) gR[i] = gt_R[b * 9 + i];
        const int n = gtq * GTN + tid;
        const float mx = mp[n * 3 + 0];
        const float my = mp[n * 3 + 1];
        const float mz = mp[n * 3 + 2];
        const float gx = fmaf(gR[0], mx, fmaf(gR[1], my, fmaf(gR[2], mz, gt_t[b * 3 + 0])));
        const float gy = fmaf(gR[3], mx, fmaf(gR[4], my, fmaf(gR[5], mz, gt_t[b * 3 + 1])));
        const float gz = fmaf(gR[6], mx, fmaf(gR[7], my, fmaf(gR[8], mz, gt_t[b * 3 + 2])));
        const float gn = fmaf(gx, gx, fmaf(gy, gy, gz * gz));
        g4[tid] = make_float4(-2.0f * gx, -2.0f * gy, -2.0f * gz, gn);
    }

    // ---- this thread's P pred points ----
    float pR[9];
#pragma unroll
    for (int i = 0; i < 9; ++i) pR[i] = pred_R[b * 9 + i];
    const float ptx = pred_t[b * 3 + 0];
    const float pty = pred_t[b * 3 + 1];
    const float ptz = pred_t[b * 3 + 2];

    float px[P], py[P], pz[P], pn[P];
#pragma unroll
    for (int p = 0; p < P; ++p) {
        const int m = pch * PREDS_PER_BLK + p * BLK + tid;  // coalesced per p
        const float mx = mp[m * 3 + 0];
        const float my = mp[m * 3 + 1];
        const float mz = mp[m * 3 + 2];
        px[p] = fmaf(pR[0], mx, fmaf(pR[1], my, fmaf(pR[2], mz, ptx)));
        py[p] = fmaf(pR[3], mx, fmaf(pR[4], my, fmaf(pR[5], mz, pty)));
        pz[p] = fmaf(pR[6], mx, fmaf(pR[7], my, fmaf(pR[8], mz, ptz)));
        pn[p] = fmaf(px[p], px[p], fmaf(py[p], py[p], pz[p] * pz[p]));
    }

    __syncthreads();

    // ---- min over partition: 4 gt/iter x 8 pred = 32 pairs/lane/iter ----
    float best0[P], best1[P];
#pragma unroll
    for (int p = 0; p < P; ++p) { best0[p] = FLT_MAX; best1[p] = FLT_MAX; }

    for (int n = 0; n < GTN; n += GUNROLL) {
        float4 h0 = g4[n + 0];
        float4 h1 = g4[n + 1];
        float4 h2 = g4[n + 2];
        float4 h3 = g4[n + 3];
#pragma unroll
        for (int p = 0; p < P; ++p) {
            const float s0 = fmaf(h0.x, px[p], fmaf(h0.y, py[p], fmaf(h0.z, pz[p], h0.w)));
            const float s1 = fmaf(h1.x, px[p], fmaf(h1.y, py[p], fmaf(h1.z, pz[p], h1.w)));
            const float s2 = fmaf(h2.x, px[p], fmaf(h2.y, py[p], fmaf(h2.z, pz[p], h2.w)));
            const float s3 = fmaf(h3.x, px[p], fmaf(h3.y, py[p], fmaf(h3.z, pz[p], h3.w)));
            best0[p] = fminf(best0[p], fminf(s0, s1));   // v_min3_f32
            best1[p] = fminf(best1[p], fminf(s2, s3));   // v_min3_f32
        }
    }

#pragma unroll
    for (int p = 0; p < P; ++p) {
        const float smin = fminf(best0[p], best1[p]);
        const float d2 = fmaxf(pn[p] + smin, 0.0f);
        const int m = pch * PREDS_PER_BLK + p * BLK + tid;
        pmin[gtq * NPRED + b * MPTS + m] = d2;   // coalesced
    }
}

// Kernel 2: per pred point, min over the 32 partials -> sqrt -> block sums.
__global__ __launch_bounds__(1024) void adds_finish1(
    const float* __restrict__ pmin, float* __restrict__ partial)
{
    __shared__ float wsum[16];
    const int tid = threadIdx.x;
    const int g = blockIdx.x * 1024 + tid;
    float m0 = FLT_MAX, m1 = FLT_MAX;
#pragma unroll
    for (int q = 0; q < GTQ; q += 2) {
        m0 = fminf(m0, pmin[(q + 0) * NPRED + g]);
        m1 = fminf(m1, pmin[(q + 1) * NPRED + g]);
    }
    float s = sqrtf(fminf(m0, m1));
#pragma unroll
    for (int off = 32; off > 0; off >>= 1) s += __shfl_down(s, off, 64);
    if ((tid & 63) == 0) wsum[tid >> 6] = s;
    __syncthreads();
    if (tid == 0) {
        float t = 0.0f;
#pragma unroll
        for (int w = 0; w < 16; ++w) t += wsum[w];
        partial[blockIdx.x] = t;
    }
}

// Kernel 3: 64 partials -> mean.
__global__ __launch_bounds__(64) void adds_finish2(
    const float* __restrict__ partial, float* __restrict__ out)
{
    float s = partial[threadIdx.x];
#pragma unroll
    for (int off = 32; off > 0; off >>= 1) s += __shfl_down(s, off, 64);
    if (threadIdx.x == 0) out[0] = s * (1.0f / (float)NPRED);
}

extern "C" void kernel_launch(void* const* d_in, const int* in_sizes, int n_in,
                              void* d_out, int out_size, void* d_ws, size_t ws_size,
                              hipStream_t stream) {
    const float* pred_R = (const float*)d_in[0];
    const float* pred_t = (const float*)d_in[1];
    const float* gt_R   = (const float*)d_in[2];
    const float* gt_t   = (const float*)d_in[3];
    const float* mp     = (const float*)d_in[4];
    float* out = (float*)d_out;

    char* ws = (char*)d_ws;
    float* pmin    = (float*)ws;                                  // 32*64K*4 = 8 MB
    float* partial = (float*)(ws + (size_t)GTQ * NPRED * 4);      // 64 floats

    adds_main<<<dim3(NB * PCH * GTQ), dim3(BLK), 0, stream>>>(
        pred_R, pred_t, gt_R, gt_t, mp, pmin);
    adds_finish1<<<dim3(64), dim3(1024), 0, stream>>>(pmin, partial);
    adds_finish2<<<dim3(1), dim3(64), 0, stream>>>(partial, out);
}

// Round 7
// 22.538 us; speedup vs baseline: 1.4678x; 1.4440x over previous
//
#include <hip/hip_runtime.h>
#include <hip/hip_bf16.h>
#include <float.h>

// Problem constants: B=16, M=4096.
#define NB 16
#define MPTS 4096
#define NPRED (NB * MPTS)       // 65536 pred points
#define GTQ 4                   // gt quarters (one per block)
#define GTN 1024                // gt points per block
#define NT 32                   // MFMA tiles of 32 gt each
#define BLK 256                 // 4 waves
#define FRAGS 4                 // B-fragments (preds) per wave: 4*32 = 128
#define PREDS_PER_BLK 512       // 4 waves * 128
#define PGRP 8                  // pred groups per batch (4096/512)

typedef _Float16 half8 __attribute__((ext_vector_type(8)));
typedef float f32x16 __attribute__((ext_vector_type(16)));

// Split x into f16 hi + f16 lo (x ~= hi + lo, |lo| <= ulp16(x)/2).
__device__ inline void split16(float x, _Float16& hi, _Float16& lo) {
    hi = (_Float16)x;
    lo = (_Float16)(x - (float)hi);
}

// Main kernel: one block = (batch b, 512-pred group, gt quarter).
// Score matrix S[gt][pred] = gn - 2 p.g via mfma_f32_32x32x16_f16 with
// hi/lo split K-slots:
//  A (gt rows):  k0-2 hi_u, k3-5 hi_u, k6-8 lo_u, k9 gn_hi, k10 gn_lo, k11-15 0
//  B (pred cols):k0-2 hi_p, k3-5 lo_p, k6-8 hi_p, k9 1,     k10 1,     k11-15 0
// where u = -2g. f16*f16 products are exact in f32; dropped lo*lo ~ 1e-5.
// Per tile: 1 ds_read_b128 (A) + 4 MFMA (4 B-frags) + 32 v_min3 folds.
__global__ __launch_bounds__(BLK) void adds_mfma(
    const float* __restrict__ pred_R, const float* __restrict__ pred_t,
    const float* __restrict__ gt_R,   const float* __restrict__ gt_t,
    const float* __restrict__ mp,     float* __restrict__ pmin)
{
    __shared__ half8 aT[NT * 64];        // 32 KB, [tile][vlane] lane-read order

    const int bid = blockIdx.x;
    const int gtq = bid & (GTQ - 1);
    const int pg  = (bid >> 2) & (PGRP - 1);
    const int b   = bid >> 5;
    const int tid = threadIdx.x;
    const int ln  = tid & 63;
    const int wv  = tid >> 6;

    // ---- stage A tiles (gt side) into LDS ----
    {
        float gR[9];
#pragma unroll
        for (int i = 0; i < 9; ++i) gR[i] = gt_R[b * 9 + i];
        const float gtx = gt_t[b * 3 + 0];
        const float gty = gt_t[b * 3 + 1];
        const float gtz = gt_t[b * 3 + 2];

#pragma unroll
        for (int w = 0; w < (NT * 64) / BLK; ++w) {   // 8 vlanes per thread
            const int v  = w * BLK + tid;             // 0..2047
            const int t  = v >> 6;
            const int vl = v & 63;
            const int n  = gtq * GTN + t * 32 + (vl & 31);
            const float mx = mp[n * 3 + 0];
            const float my = mp[n * 3 + 1];
            const float mz = mp[n * 3 + 2];
            const float gx = fmaf(gR[0], mx, fmaf(gR[1], my, fmaf(gR[2], mz, gtx)));
            const float gy = fmaf(gR[3], mx, fmaf(gR[4], my, fmaf(gR[5], mz, gty)));
            const float gz = fmaf(gR[6], mx, fmaf(gR[7], my, fmaf(gR[8], mz, gtz)));
            const float gn = fmaf(gx, gx, fmaf(gy, gy, gz * gz));
            const float ux = -2.0f * gx, uy = -2.0f * gy, uz = -2.0f * gz;
            _Float16 hux, lux, huy, luy, huz, luz, gnh, gnl;
            split16(ux, hux, lux);
            split16(uy, huy, luy);
            split16(uz, huz, luz);
            split16(gn, gnh, gnl);
            half8 pk;
            if ((vl >> 5) == 0) {        // k0..7
                pk[0] = hux; pk[1] = huy; pk[2] = huz;
                pk[3] = hux; pk[4] = huy; pk[5] = huz;
                pk[6] = lux; pk[7] = luy;
            } else {                      // k8..15
                pk[0] = luz; pk[1] = gnh; pk[2] = gnl;
                pk[3] = (_Float16)0.0f; pk[4] = (_Float16)0.0f;
                pk[5] = (_Float16)0.0f; pk[6] = (_Float16)0.0f;
                pk[7] = (_Float16)0.0f;
            }
            aT[v] = pk;
        }
    }

    // ---- B-fragments (pred side), constant across tiles ----
    float pR[9];
#pragma unroll
    for (int i = 0; i < 9; ++i) pR[i] = pred_R[b * 9 + i];
    const float ptx = pred_t[b * 3 + 0];
    const float pty = pred_t[b * 3 + 1];
    const float ptz = pred_t[b * 3 + 2];

    half8 bf[FRAGS];
    float pn[FRAGS];
    const int kh = ln >> 5;
#pragma unroll
    for (int f = 0; f < FRAGS; ++f) {
        const int predl = pg * PREDS_PER_BLK + wv * 128 + f * 32 + (ln & 31);
        const float mx = mp[predl * 3 + 0];
        const float my = mp[predl * 3 + 1];
        const float mz = mp[predl * 3 + 2];
        const float px = fmaf(pR[0], mx, fmaf(pR[1], my, fmaf(pR[2], mz, ptx)));
        const float py = fmaf(pR[3], mx, fmaf(pR[4], my, fmaf(pR[5], mz, pty)));
        const float pz = fmaf(pR[6], mx, fmaf(pR[7], my, fmaf(pR[8], mz, ptz)));
        pn[f] = fmaf(px, px, fmaf(py, py, pz * pz));
        _Float16 hpx, lpx, hpy, lpy, hpz, lpz;
        split16(px, hpx, lpx);
        split16(py, hpy, lpy);
        split16(pz, hpz, lpz);
        half8 v;
        if (kh == 0) {                    // k0..7
            v[0] = hpx; v[1] = hpy; v[2] = hpz;
            v[3] = lpx; v[4] = lpy; v[5] = lpz;
            v[6] = hpx; v[7] = hpy;
        } else {                          // k8..15
            v[0] = hpz; v[1] = (_Float16)1.0f; v[2] = (_Float16)1.0f;
            v[3] = (_Float16)0.0f; v[4] = (_Float16)0.0f;
            v[5] = (_Float16)0.0f; v[6] = (_Float16)0.0f;
            v[7] = (_Float16)0.0f;
        }
        bf[f] = v;
    }

    __syncthreads();

    // ---- MFMA loop over 32 gt tiles ----
    f32x16 zc;
#pragma unroll
    for (int i = 0; i < 16; ++i) zc[i] = 0.0f;

    float best[FRAGS][8];
#pragma unroll
    for (int f = 0; f < FRAGS; ++f)
#pragma unroll
        for (int j = 0; j < 8; ++j) best[f][j] = FLT_MAX;

    half8 a_cur = aT[ln];
    for (int t = 0; t < NT; ++t) {
        const half8 a_nxt = (t + 1 < NT) ? aT[(t + 1) * 64 + ln] : a_cur;
        const f32x16 d0 = __builtin_amdgcn_mfma_f32_32x32x16_f16(a_cur, bf[0], zc, 0, 0, 0);
        const f32x16 d1 = __builtin_amdgcn_mfma_f32_32x32x16_f16(a_cur, bf[1], zc, 0, 0, 0);
        const f32x16 d2 = __builtin_amdgcn_mfma_f32_32x32x16_f16(a_cur, bf[2], zc, 0, 0, 0);
        const f32x16 d3 = __builtin_amdgcn_mfma_f32_32x32x16_f16(a_cur, bf[3], zc, 0, 0, 0);
#pragma unroll
        for (int j = 0; j < 8; ++j) {
            best[0][j] = fminf(best[0][j], fminf(d0[2 * j], d0[2 * j + 1]));
            best[1][j] = fminf(best[1][j], fminf(d1[2 * j], d1[2 * j + 1]));
            best[2][j] = fminf(best[2][j], fminf(d2[2 * j], d2[2 * j + 1]));
            best[3][j] = fminf(best[3][j], fminf(d3[2 * j], d3[2 * j + 1]));
        }
        a_cur = a_nxt;
    }

    // ---- epilogue: fold 8 regs, merge lane halves, add pn, store ----
#pragma unroll
    for (int f = 0; f < FRAGS; ++f) {
        float r = fminf(fminf(fminf(best[f][0], best[f][1]), fminf(best[f][2], best[f][3])),
                        fminf(fminf(best[f][4], best[f][5]), fminf(best[f][6], best[f][7])));
        r = fminf(r, __shfl_xor(r, 32, 64));
        const float d2v = fmaxf(pn[f] + r, 0.0f);
        if (ln < 32) {
            const int predl = pg * PREDS_PER_BLK + wv * 128 + f * 32 + ln;
            pmin[gtq * NPRED + b * MPTS + predl] = d2v;
        }
    }
}

// Kernel 2: per pred point, min over the 4 partials -> sqrt -> block sums.
__global__ __launch_bounds__(1024) void adds_finish1(
    const float* __restrict__ pmin, float* __restrict__ partial)
{
    __shared__ float wsum[16];
    const int tid = threadIdx.x;
    const int g = blockIdx.x * 1024 + tid;
    const float m0 = fminf(pmin[0 * NPRED + g], pmin[1 * NPRED + g]);
    const float m1 = fminf(pmin[2 * NPRED + g], pmin[3 * NPRED + g]);
    float s = sqrtf(fminf(m0, m1));
#pragma unroll
    for (int off = 32; off > 0; off >>= 1) s += __shfl_down(s, off, 64);
    if ((tid & 63) == 0) wsum[tid >> 6] = s;
    __syncthreads();
    if (tid == 0) {
        float t = 0.0f;
#pragma unroll
        for (int w = 0; w < 16; ++w) t += wsum[w];
        partial[blockIdx.x] = t;
    }
}

// Kernel 3: 64 partials -> mean.
__global__ __launch_bounds__(64) void adds_finish2(
    const float* __restrict__ partial, float* __restrict__ out)
{
    float s = partial[threadIdx.x];
#pragma unroll
    for (int off = 32; off > 0; off >>= 1) s += __shfl_down(s, off, 64);
    if (threadIdx.x == 0) out[0] = s * (1.0f / (float)NPRED);
}

extern "C" void kernel_launch(void* const* d_in, const int* in_sizes, int n_in,
                              void* d_out, int out_size, void* d_ws, size_t ws_size,
                              hipStream_t stream) {
    const float* pred_R = (const float*)d_in[0];
    const float* pred_t = (const float*)d_in[1];
    const float* gt_R   = (const float*)d_in[2];
    const float* gt_t   = (const float*)d_in[3];
    const float* mp     = (const float*)d_in[4];
    float* out = (float*)d_out;

    char* ws = (char*)d_ws;
    float* pmin    = (float*)ws;                                  // 4*64K*4 = 1 MB
    float* partial = (float*)(ws + (size_t)GTQ * NPRED * 4);      // 64 floats

    // grid: b(16) x pred-group(8) x gtq(4) = 512 blocks
    adds_mfma<<<dim3(NB * PGRP * GTQ), dim3(BLK), 0, stream>>>(
        pred_R, pred_t, gt_R, gt_t, mp, pmin);
    adds_finish1<<<dim3(64), dim3(1024), 0, stream>>>(pmin, partial);
    adds_finish2<<<dim3(1), dim3(64), 0, stream>>>(partial, out);
}